// Round 6
// baseline (207.485 us; speedup 1.0000x reference)
//
#include <hip/hip_runtime.h>
#include <stdint.h>

#define B_ 64
#define S_ 512
#define EMB_ 256
#define NIN_ 7
#define NOUT_ 4
#define HID_ 512
#define VOCAB_ 1000
#define VP_ 1024          // vocab padded to 1024 rows
#define NG_ 2048          // table cols: [fwd z/f interleaved 1024 | bwd 1024]
#define M_ (B_ * S_)

typedef __bf16 bf16x8 __attribute__((ext_vector_type(8)));
typedef float floatx4 __attribute__((ext_vector_type(4)));
typedef unsigned short u16x8 __attribute__((ext_vector_type(8)));

__device__ __forceinline__ unsigned short f2bf(float f) {
    unsigned u = __float_as_uint(f);
    u += 0x7FFFu + ((u >> 16) & 1u);   // RNE
    return (unsigned short)(u >> 16);
}
__device__ __forceinline__ float bf2f(unsigned short h) {
    return __uint_as_float(((unsigned)h) << 16);
}
__device__ __forceinline__ float rcp_(float x) { return __builtin_amdgcn_rcpf(x); }
__device__ __forceinline__ float sigmoidf_(float x) {
    return rcp_(1.0f + __expf(-x));
}
__device__ __forceinline__ float tanhf_(float x) {
    float ax = fabsf(x);
    float e = __expf(-2.0f * ax);
    float t = (1.0f - e) * rcp_(1.0f + e);
    return copysignf(t, x);
}

// virtual table col v (0..2047): part = v>>10 (0 fwd Wf, 1 bwd Wb),
// m = v&1023, j = m>>1, zf = m&1, source col c = zf ? 512+j : j.
// G[row][2j] = z-gate, G[row][2j+1] = f-gate (fwd); +1024 for bwd.
// MFMA fragment-order chunks: chunk = ((tile*8 + kt)*8 + grp16)*512 shorts;
// lane l = 16*kchunk + idx15 holds 8 bf16 (k = kt*32+kchunk*8+q) at l*8+q.

// ---------------- K1: prep: Aemb frags, WT frags, W7/bvec, flags ------------
__global__ __launch_bounds__(256) void prep(
    const float* __restrict__ emb, const float* __restrict__ Wn,
    const float* __restrict__ bn, const float* __restrict__ Wf,
    const float* __restrict__ bfv, const float* __restrict__ Wb,
    const float* __restrict__ bb,
    unsigned short* __restrict__ Aemb, unsigned short* __restrict__ WT,
    float* __restrict__ W7, float* __restrict__ bvec, int* __restrict__ flags) {
    int bid = blockIdx.x;
    int tid = threadIdx.x;

    if (bid < 64) {                         // ---- Aemb: rows 16*bid..+15
        int g = bid;
#pragma unroll
        for (int half = 0; half < 2; ++half) {
            int t = tid + 256 * half;
            int r15 = t & 15;
            int kchunk = (t >> 4) & 3;
            int kt = t >> 6;                // 0..7
            int row = g * 16 + r15;
            int k0 = kt * 32 + kchunk * 8;
            unsigned short p[8];
            if (row < VOCAB_) {
                float4 a = *(const float4*)(emb + (size_t)row * EMB_ + k0);
                float4 b = *(const float4*)(emb + (size_t)row * EMB_ + k0 + 4);
                p[0]=f2bf(a.x); p[1]=f2bf(a.y); p[2]=f2bf(a.z); p[3]=f2bf(a.w);
                p[4]=f2bf(b.x); p[5]=f2bf(b.y); p[6]=f2bf(b.z); p[7]=f2bf(b.w);
            } else {
#pragma unroll
                for (int q = 0; q < 8; ++q) p[q] = 0;
            }
            size_t chunk = ((size_t)(g >> 3) * 8 + kt) * 8 + (g & 7);
            *(u16x8*)(Aemb + chunk * 512 + (16 * kchunk + r15) * 8) =
                *(const u16x8*)p;
        }
    } else if (bid < 192) {                 // ---- WT: cols 16*(bid-64)..+15
        int g = bid - 64;
#pragma unroll
        for (int half = 0; half < 2; ++half) {
            int t = tid + 256 * half;
            int v15 = t & 15;
            int kchunk = (t >> 4) & 3;
            int kt = t >> 6;
            int v = g * 16 + v15;
            int part = v >> 10;
            int m = v & 1023;
            int j = m >> 1;
            int c = (m & 1) ? (512 + j) : j;
            const float* W = part ? Wb : Wf;
            int k0 = kt * 32 + kchunk * 8;
            unsigned short p[8];
#pragma unroll
            for (int q = 0; q < 8; ++q)
                p[q] = f2bf(W[(size_t)(k0 + q) * 1536 + c]);
            size_t chunk = ((size_t)(g >> 3) * 8 + kt) * 8 + (g & 7);
            *(u16x8*)(WT + chunk * 512 + (16 * kchunk + v15) * 8) =
                *(const u16x8*)p;
        }
    } else {                                // ---- W7 (7 x 2048) + bvec + flags
        if (tid < B_) flags[tid] = 0;
        float wn[NIN_][NOUT_];
#pragma unroll
        for (int i = 0; i < NIN_; ++i)
#pragma unroll
            for (int q = 0; q < NOUT_; ++q) wn[i][q] = Wn[i * NOUT_ + q];
        float bnr[NOUT_];
#pragma unroll
        for (int q = 0; q < NOUT_; ++q) bnr[q] = bn[q];
#pragma unroll
        for (int it = 0; it < 8; ++it) {
            int v = tid + 256 * it;
            int part = v >> 10;
            int m = v & 1023;
            int j = m >> 1;
            int c = (m & 1) ? (512 + j) : j;
            const float* W = part ? Wb : Wf;
            float wnum[NOUT_];
#pragma unroll
            for (int q = 0; q < NOUT_; ++q)
                wnum[q] = W[(size_t)(256 + q) * 1536 + c];
            float bv = part ? bb[c] : bfv[c];
#pragma unroll
            for (int q = 0; q < NOUT_; ++q) bv += bnr[q] * wnum[q];
            bvec[v] = bv;
#pragma unroll
            for (int i = 0; i < NIN_; ++i) {
                float s = 0.f;
#pragma unroll
                for (int q = 0; q < NOUT_; ++q) s += wn[i][q] * wnum[q];
                W7[(size_t)i * NG_ + v] = s;
            }
        }
    }
}

// ---------------- K2: G = Aemb @ WT + bvec (1024 x 2048, K=256) -------------
__global__ __launch_bounds__(256) void gemmG(
    const unsigned short* __restrict__ Aemb, const unsigned short* __restrict__ WT,
    const float* __restrict__ bvec, unsigned short* __restrict__ G) {
    int bid = blockIdx.x;                   // 128 = 8 mtiles x 16 ntiles
    int mtile = bid & 7;
    int ntile = bid >> 3;
    int r0 = mtile * 128;
    int n0 = ntile * 128;
    int tid = threadIdx.x;
    int lane = tid & 63, wave = tid >> 6;
    int wm = wave & 1, wn = wave >> 1;
    int rl = lane & 15;

    const unsigned short* pa = Aemb + ((size_t)mtile * 64 + 4 * wm) * 512 + lane * 8;
    const unsigned short* pb = WT + ((size_t)ntile * 64 + 4 * wn) * 512 + lane * 8;

    floatx4 acc[4][4];
#pragma unroll
    for (int mi = 0; mi < 4; ++mi)
#pragma unroll
        for (int ni = 0; ni < 4; ++ni) acc[mi][ni] = (floatx4){0.f, 0.f, 0.f, 0.f};

    bf16x8 afc[4], bfc[4], afn[4], bfn[4];
#pragma unroll
    for (int mi = 0; mi < 4; ++mi) afc[mi] = *(const bf16x8*)(pa + mi * 512);
#pragma unroll
    for (int ni = 0; ni < 4; ++ni) bfc[ni] = *(const bf16x8*)(pb + ni * 512);

#pragma unroll
    for (int kt = 0; kt < 8; ++kt) {
        if (kt < 7) {
#pragma unroll
            for (int mi = 0; mi < 4; ++mi)
                afn[mi] = *(const bf16x8*)(pa + (size_t)(kt + 1) * 4096 + mi * 512);
#pragma unroll
            for (int ni = 0; ni < 4; ++ni)
                bfn[ni] = *(const bf16x8*)(pb + (size_t)(kt + 1) * 4096 + ni * 512);
        }
#pragma unroll
        for (int mi = 0; mi < 4; ++mi)
#pragma unroll
            for (int ni = 0; ni < 4; ++ni)
                acc[mi][ni] = __builtin_amdgcn_mfma_f32_16x16x32_bf16(afc[mi], bfc[ni], acc[mi][ni], 0, 0, 0);
        if (kt < 7) {
#pragma unroll
            for (int mi = 0; mi < 4; ++mi) afc[mi] = afn[mi];
#pragma unroll
            for (int ni = 0; ni < 4; ++ni) bfc[ni] = bfn[ni];
        }
    }

    // C/D: col = lane&15, row = (lane>>4)*4 + reg  [m89/m91]
#pragma unroll
    for (int ni = 0; ni < 4; ++ni) {
        int n = n0 + 64 * wn + 16 * ni + rl;
        float bv = bvec[n];
#pragma unroll
        for (int mi = 0; mi < 4; ++mi) {
            int rb = r0 + 64 * wm + 16 * mi + (lane >> 4) * 4;
#pragma unroll
            for (int v = 0; v < 4; ++v)
                G[(size_t)(rb + v) * NG_ + n] = f2bf(acc[mi][ni][v] + bv);
        }
    }
}

// ---------------- K3: gather-scan + last-block fold/final -------------------
// 512 blocks (b x 8 chunks) x 512 thr; the 8th finisher per b does the fold,
// backward single-step, and Wo reduction (rocPRIM last-block pattern).
__global__ __launch_bounds__(512) void scan_final(
    const float* __restrict__ X, const unsigned short* __restrict__ G,
    const float* __restrict__ W7, const float* __restrict__ Wo,
    const float* __restrict__ bo, float* __restrict__ PQ,
    int* __restrict__ flags, float* __restrict__ out) {
    __shared__ float LX[512];               // 64 steps x 8 floats; reused as red
    __shared__ int isLast;
    int bid = blockIdx.x;
    int b = bid >> 3, chunk = bid & 7;
    int s0 = chunk * 64;
    int j = threadIdx.x;                    // chain 0..511

    LX[j] = X[((size_t)b * S_ + s0 + (j >> 3)) * 8 + (j & 7)];
    __syncthreads();

    float2 w7p[NIN_];
#pragma unroll
    for (int i = 0; i < NIN_; ++i)
        w7p[i] = *(const float2*)(W7 + (size_t)i * NG_ + 2 * j);

    float P = 1.f, Q = 0.f;
    int ev0 = (int)LX[0];
    unsigned gp = *(const unsigned*)(G + (size_t)ev0 * NG_ + 2 * j);
#pragma unroll 4
    for (int s = 0; s < 64; ++s) {
        unsigned gpc = gp;
        if (s < 63) {
            int evn = (int)LX[(s + 1) * 8];
            gp = *(const unsigned*)(G + (size_t)evn * NG_ + 2 * j);
        }
        float gz = bf2f((unsigned short)(gpc & 0xffffu));
        float gf = bf2f((unsigned short)(gpc >> 16));
#pragma unroll
        for (int i = 0; i < NIN_; ++i) {
            float x = LX[s * 8 + 1 + i];
            gz += x * w7p[i].x;
            gf += x * w7p[i].y;
        }
        float z = tanhf_(gz);
        float f = sigmoidf_(gf);
        Q = f * Q + (1.f - f) * z;
        P *= f;
    }
    ((float2*)PQ)[(size_t)bid * 512 + j] = make_float2(P, Q);

    __threadfence();                        // release PQ stores (device scope)
    __syncthreads();                        // LX free for reuse as red
    if (j == 0) {
        int old = atomicAdd(flags + b, 1);
        isLast = (old == 7);
    }
    __syncthreads();
    if (!isLast) return;
    __threadfence();                        // acquire: see other chunks' PQ

    // fold 8 chunk affines in order
    float h = 0.f;
#pragma unroll
    for (int c = 0; c < 8; ++c) {
        float2 pq = ((const float2*)PQ)[((size_t)b * 8 + c) * 512 + j];
        h = pq.x * h + pq.y;
    }

    // backward hidden: single step at s = S-1
    const float* xr = X + ((size_t)b * S_ + (S_ - 1)) * 8;
    int ev = (int)xr[0];
    unsigned gpc = *(const unsigned*)(G + (size_t)ev * NG_ + 1024 + 2 * j);
    float gz = bf2f((unsigned short)(gpc & 0xffffu));
    float gf = bf2f((unsigned short)(gpc >> 16));
#pragma unroll
    for (int i = 0; i < NIN_; ++i) {
        float2 w = *(const float2*)(W7 + (size_t)i * NG_ + 1024 + 2 * j);
        float x = xr[1 + i];
        gz += x * w.x;
        gf += x * w.y;
    }
    float hb = (1.f - sigmoidf_(gf)) * tanhf_(gz);

    float* red = LX;
    red[j] = h * Wo[j] + hb * Wo[512 + j];
    __syncthreads();
    for (int off = 256; off > 0; off >>= 1) {
        if (j < off) red[j] += red[j + off];
        __syncthreads();
    }
    if (j == 0) out[b] = red[0] + bo[0];
}

extern "C" void kernel_launch(void* const* d_in, const int* in_sizes, int n_in,
                              void* d_out, int out_size, void* d_ws, size_t ws_size,
                              hipStream_t stream) {
    const float* X   = (const float*)d_in[0];
    const float* emb = (const float*)d_in[1];
    const float* Wn  = (const float*)d_in[2];
    const float* bn  = (const float*)d_in[3];
    const float* Wf  = (const float*)d_in[4];
    const float* bfv = (const float*)d_in[5];
    const float* Wb  = (const float*)d_in[6];
    const float* bb  = (const float*)d_in[7];
    const float* Wo  = (const float*)d_in[8];
    const float* bo  = (const float*)d_in[9];
    float* out = (float*)d_out;

    size_t off_A  = 0;
    size_t off_WT = off_A  + (size_t)VP_ * EMB_ * 2;          // 512 KB
    size_t off_G  = off_WT + (size_t)NG_ * EMB_ * 2;          // +1 MB
    size_t off_W7 = off_G  + (size_t)VP_ * NG_ * 2;           // +4 MB
    size_t off_bv = off_W7 + (size_t)NIN_ * NG_ * 4;          // +56 KB
    size_t off_PQ = off_bv + (size_t)NG_ * 4;                 // +8 KB
    size_t off_fl = off_PQ + (size_t)B_ * 8 * 512 * 2 * sizeof(float);  // +2 MB
    size_t need   = off_fl + B_ * sizeof(int);
    if (ws_size < need) return;

    unsigned short* Aemb = (unsigned short*)((char*)d_ws + off_A);
    unsigned short* WT   = (unsigned short*)((char*)d_ws + off_WT);
    unsigned short* G    = (unsigned short*)((char*)d_ws + off_G);
    float*          W7   = (float*)((char*)d_ws + off_W7);
    float*          bvec = (float*)((char*)d_ws + off_bv);
    float*          PQ   = (float*)((char*)d_ws + off_PQ);
    int*            flags= (int*)((char*)d_ws + off_fl);

    prep<<<193, 256, 0, stream>>>(emb, Wn, bn, Wf, bfv, Wb, bb,
                                  Aemb, WT, W7, bvec, flags);
    gemmG<<<128, 256, 0, stream>>>(Aemb, WT, bvec, G);
    scan_final<<<512, 512, 0, stream>>>(X, G, W7, Wo, bo, PQ, flags, out);
}

// Round 7
// 114.172 us; speedup vs baseline: 1.8173x; 1.8173x over previous
//
#include <hip/hip_runtime.h>
#include <stdint.h>

#define B_ 64
#define S_ 512
#define EMB_ 256
#define NIN_ 7
#define NOUT_ 4
#define HID_ 512
#define VOCAB_ 1000
#define VP_ 1024          // vocab padded to 1024 rows
#define NG_ 2048          // table cols: [fwd z/f interleaved 1024 | bwd 1024]
#define M_ (B_ * S_)

typedef __bf16 bf16x8 __attribute__((ext_vector_type(8)));
typedef float floatx4 __attribute__((ext_vector_type(4)));
typedef unsigned short u16x8 __attribute__((ext_vector_type(8)));

__device__ __forceinline__ unsigned short f2bf(float f) {
    unsigned u = __float_as_uint(f);
    u += 0x7FFFu + ((u >> 16) & 1u);   // RNE
    return (unsigned short)(u >> 16);
}
__device__ __forceinline__ float bf2f(unsigned short h) {
    return __uint_as_float(((unsigned)h) << 16);
}
__device__ __forceinline__ float rcp_(float x) { return __builtin_amdgcn_rcpf(x); }
__device__ __forceinline__ float sigmoidf_(float x) {
    return rcp_(1.0f + __expf(-x));
}
__device__ __forceinline__ float tanhf_(float x) {
    float ax = fabsf(x);
    float e = __expf(-2.0f * ax);
    float t = (1.0f - e) * rcp_(1.0f + e);
    return copysignf(t, x);
}

// virtual table col v (0..2047): part = v>>10 (0 fwd Wf, 1 bwd Wb),
// m = v&1023, j = m>>1, zf = m&1, source col c = zf ? 512+j : j.
// G[row][2j] = z-gate, G[row][2j+1] = f-gate (fwd); +1024 for bwd.
// MFMA fragment-order chunks: chunk = ((tile*8 + kt)*8 + grp16)*512 shorts;
// lane l = 16*kchunk + idx15 holds 8 bf16 (k = kt*32+kchunk*8+q) at l*8+q.
//
// NOTE (R6 post-mortem): do NOT fuse final_out into scan via device-scope
// fences — __threadfence() across non-coherent per-XCD L2s costs ~130 µs of
// writeback serialization. The kernel-boundary handoff is the cheap version.

// ---------------- K1: prep: Aemb frags, WT frags, W7/bvec -------------------
__global__ __launch_bounds__(256) void prep(
    const float* __restrict__ emb, const float* __restrict__ Wn,
    const float* __restrict__ bn, const float* __restrict__ Wf,
    const float* __restrict__ bfv, const float* __restrict__ Wb,
    const float* __restrict__ bb,
    unsigned short* __restrict__ Aemb, unsigned short* __restrict__ WT,
    float* __restrict__ W7, float* __restrict__ bvec) {
    int bid = blockIdx.x;
    int tid = threadIdx.x;

    if (bid < 64) {                         // ---- Aemb: rows 16*bid..+15
        int g = bid;
#pragma unroll
        for (int half = 0; half < 2; ++half) {
            int t = tid + 256 * half;
            int r15 = t & 15;
            int kchunk = (t >> 4) & 3;
            int kt = t >> 6;                // 0..7
            int row = g * 16 + r15;
            int k0 = kt * 32 + kchunk * 8;
            unsigned short p[8];
            if (row < VOCAB_) {
                float4 a = *(const float4*)(emb + (size_t)row * EMB_ + k0);
                float4 b = *(const float4*)(emb + (size_t)row * EMB_ + k0 + 4);
                p[0]=f2bf(a.x); p[1]=f2bf(a.y); p[2]=f2bf(a.z); p[3]=f2bf(a.w);
                p[4]=f2bf(b.x); p[5]=f2bf(b.y); p[6]=f2bf(b.z); p[7]=f2bf(b.w);
            } else {
#pragma unroll
                for (int q = 0; q < 8; ++q) p[q] = 0;
            }
            size_t chunk = ((size_t)(g >> 3) * 8 + kt) * 8 + (g & 7);
            *(u16x8*)(Aemb + chunk * 512 + (16 * kchunk + r15) * 8) =
                *(const u16x8*)p;
        }
    } else if (bid < 192) {                 // ---- WT: cols 16*(bid-64)..+15
        int g = bid - 64;
#pragma unroll
        for (int half = 0; half < 2; ++half) {
            int t = tid + 256 * half;
            int v15 = t & 15;
            int kchunk = (t >> 4) & 3;
            int kt = t >> 6;
            int v = g * 16 + v15;
            int part = v >> 10;
            int m = v & 1023;
            int j = m >> 1;
            int c = (m & 1) ? (512 + j) : j;
            const float* W = part ? Wb : Wf;
            int k0 = kt * 32 + kchunk * 8;
            unsigned short p[8];
#pragma unroll
            for (int q = 0; q < 8; ++q)
                p[q] = f2bf(W[(size_t)(k0 + q) * 1536 + c]);
            size_t chunk = ((size_t)(g >> 3) * 8 + kt) * 8 + (g & 7);
            *(u16x8*)(WT + chunk * 512 + (16 * kchunk + v15) * 8) =
                *(const u16x8*)p;
        }
    } else {                                // ---- W7 (7 x 2048) + bvec (2048)
        float wn[NIN_][NOUT_];
#pragma unroll
        for (int i = 0; i < NIN_; ++i)
#pragma unroll
            for (int q = 0; q < NOUT_; ++q) wn[i][q] = Wn[i * NOUT_ + q];
        float bnr[NOUT_];
#pragma unroll
        for (int q = 0; q < NOUT_; ++q) bnr[q] = bn[q];
#pragma unroll
        for (int it = 0; it < 8; ++it) {
            int v = tid + 256 * it;
            int part = v >> 10;
            int m = v & 1023;
            int j = m >> 1;
            int c = (m & 1) ? (512 + j) : j;
            const float* W = part ? Wb : Wf;
            float wnum[NOUT_];
#pragma unroll
            for (int q = 0; q < NOUT_; ++q)
                wnum[q] = W[(size_t)(256 + q) * 1536 + c];
            float bv = part ? bb[c] : bfv[c];
#pragma unroll
            for (int q = 0; q < NOUT_; ++q) bv += bnr[q] * wnum[q];
            bvec[v] = bv;
#pragma unroll
            for (int i = 0; i < NIN_; ++i) {
                float s = 0.f;
#pragma unroll
                for (int q = 0; q < NOUT_; ++q) s += wn[i][q] * wnum[q];
                W7[(size_t)i * NG_ + v] = s;
            }
        }
    }
}

// ---------------- K2: G = Aemb @ WT + bvec (1024 x 2048, K=256) -------------
// barrier-free register-double-buffered K-loop.
__global__ __launch_bounds__(256) void gemmG(
    const unsigned short* __restrict__ Aemb, const unsigned short* __restrict__ WT,
    const float* __restrict__ bvec, unsigned short* __restrict__ G) {
    int bid = blockIdx.x;                   // 128 = 8 mtiles x 16 ntiles
    int mtile = bid & 7;
    int ntile = bid >> 3;
    int r0 = mtile * 128;
    int n0 = ntile * 128;
    int tid = threadIdx.x;
    int lane = tid & 63, wave = tid >> 6;
    int wm = wave & 1, wn = wave >> 1;
    int rl = lane & 15;

    const unsigned short* pa = Aemb + ((size_t)mtile * 64 + 4 * wm) * 512 + lane * 8;
    const unsigned short* pb = WT + ((size_t)ntile * 64 + 4 * wn) * 512 + lane * 8;

    floatx4 acc[4][4];
#pragma unroll
    for (int mi = 0; mi < 4; ++mi)
#pragma unroll
        for (int ni = 0; ni < 4; ++ni) acc[mi][ni] = (floatx4){0.f, 0.f, 0.f, 0.f};

    bf16x8 afc[4], bfc[4], afn[4], bfn[4];
#pragma unroll
    for (int mi = 0; mi < 4; ++mi) afc[mi] = *(const bf16x8*)(pa + mi * 512);
#pragma unroll
    for (int ni = 0; ni < 4; ++ni) bfc[ni] = *(const bf16x8*)(pb + ni * 512);

#pragma unroll
    for (int kt = 0; kt < 8; ++kt) {
        if (kt < 7) {
#pragma unroll
            for (int mi = 0; mi < 4; ++mi)
                afn[mi] = *(const bf16x8*)(pa + (size_t)(kt + 1) * 4096 + mi * 512);
#pragma unroll
            for (int ni = 0; ni < 4; ++ni)
                bfn[ni] = *(const bf16x8*)(pb + (size_t)(kt + 1) * 4096 + ni * 512);
        }
#pragma unroll
        for (int mi = 0; mi < 4; ++mi)
#pragma unroll
            for (int ni = 0; ni < 4; ++ni)
                acc[mi][ni] = __builtin_amdgcn_mfma_f32_16x16x32_bf16(afc[mi], bfc[ni], acc[mi][ni], 0, 0, 0);
        if (kt < 7) {
#pragma unroll
            for (int mi = 0; mi < 4; ++mi) afc[mi] = afn[mi];
#pragma unroll
            for (int ni = 0; ni < 4; ++ni) bfc[ni] = bfn[ni];
        }
    }

    // C/D: col = lane&15, row = (lane>>4)*4 + reg  [m89/m91]
#pragma unroll
    for (int ni = 0; ni < 4; ++ni) {
        int n = n0 + 64 * wn + 16 * ni + rl;
        float bv = bvec[n];
#pragma unroll
        for (int mi = 0; mi < 4; ++mi) {
            int rb = r0 + 64 * wm + 16 * mi + (lane >> 4) * 4;
#pragma unroll
            for (int v = 0; v < 4; ++v)
                G[(size_t)(rb + v) * NG_ + n] = f2bf(acc[mi][ni][v] + bv);
        }
    }
}

// ---------------- K3: gather-scan: 512 blocks (b x 8 chunks) x 512 thr ------
__global__ __launch_bounds__(512) void scan(
    const float* __restrict__ X, const unsigned short* __restrict__ G,
    const float* __restrict__ W7, float* __restrict__ PQ) {
    __shared__ float LX[512];               // 64 steps x 8 floats
    int bid = blockIdx.x;
    int b = bid >> 3, chunk = bid & 7;
    int s0 = chunk * 64;
    int j = threadIdx.x;                    // chain 0..511

    LX[j] = X[((size_t)b * S_ + s0 + (j >> 3)) * 8 + (j & 7)];
    __syncthreads();

    float2 w7p[NIN_];
#pragma unroll
    for (int i = 0; i < NIN_; ++i)
        w7p[i] = *(const float2*)(W7 + (size_t)i * NG_ + 2 * j);

    float P = 1.f, Q = 0.f;
    int ev0 = (int)LX[0];
    unsigned gp = *(const unsigned*)(G + (size_t)ev0 * NG_ + 2 * j);
#pragma unroll 4
    for (int s = 0; s < 64; ++s) {
        unsigned gpc = gp;
        if (s < 63) {
            int evn = (int)LX[(s + 1) * 8];
            gp = *(const unsigned*)(G + (size_t)evn * NG_ + 2 * j);
        }
        float gz = bf2f((unsigned short)(gpc & 0xffffu));
        float gf = bf2f((unsigned short)(gpc >> 16));
#pragma unroll
        for (int i = 0; i < NIN_; ++i) {
            float x = LX[s * 8 + 1 + i];
            gz += x * w7p[i].x;
            gf += x * w7p[i].y;
        }
        float z = tanhf_(gz);
        float f = sigmoidf_(gf);
        Q = f * Q + (1.f - f) * z;
        P *= f;
    }
    ((float2*)PQ)[(size_t)bid * 512 + j] = make_float2(P, Q);
}

// ---------------- K4: fold chunks + backward (1 step) + Wo dot --------------
__global__ __launch_bounds__(512) void final_out(
    const float* __restrict__ X, const unsigned short* __restrict__ G,
    const float* __restrict__ W7, const float* __restrict__ Wo,
    const float* __restrict__ bo, const float* __restrict__ PQ,
    float* __restrict__ out) {
    int b = blockIdx.x;
    int j = threadIdx.x;                    // 0..511

    float h = 0.f;
#pragma unroll
    for (int c = 0; c < 8; ++c) {
        float2 pq = ((const float2*)PQ)[((size_t)b * 8 + c) * 512 + j];
        h = pq.x * h + pq.y;
    }

    const float* xr = X + ((size_t)b * S_ + (S_ - 1)) * 8;
    int ev = (int)xr[0];
    unsigned gpc = *(const unsigned*)(G + (size_t)ev * NG_ + 1024 + 2 * j);
    float gz = bf2f((unsigned short)(gpc & 0xffffu));
    float gf = bf2f((unsigned short)(gpc >> 16));
#pragma unroll
    for (int i = 0; i < NIN_; ++i) {
        float2 w = *(const float2*)(W7 + (size_t)i * NG_ + 1024 + 2 * j);
        float x = xr[1 + i];
        gz += x * w.x;
        gf += x * w.y;
    }
    float hb = (1.f - sigmoidf_(gf)) * tanhf_(gz);

    float partial = h * Wo[j] + hb * Wo[512 + j];
    __shared__ float red[512];
    red[j] = partial;
    __syncthreads();
    for (int off = 256; off > 0; off >>= 1) {
        if (j < off) red[j] += red[j + off];
        __syncthreads();
    }
    if (j == 0) out[b] = red[0] + bo[0];
}

extern "C" void kernel_launch(void* const* d_in, const int* in_sizes, int n_in,
                              void* d_out, int out_size, void* d_ws, size_t ws_size,
                              hipStream_t stream) {
    const float* X   = (const float*)d_in[0];
    const float* emb = (const float*)d_in[1];
    const float* Wn  = (const float*)d_in[2];
    const float* bn  = (const float*)d_in[3];
    const float* Wf  = (const float*)d_in[4];
    const float* bfv = (const float*)d_in[5];
    const float* Wb  = (const float*)d_in[6];
    const float* bb  = (const float*)d_in[7];
    const float* Wo  = (const float*)d_in[8];
    const float* bo  = (const float*)d_in[9];
    float* out = (float*)d_out;

    size_t off_A  = 0;
    size_t off_WT = off_A  + (size_t)VP_ * EMB_ * 2;          // 512 KB
    size_t off_G  = off_WT + (size_t)NG_ * EMB_ * 2;          // +1 MB
    size_t off_W7 = off_G  + (size_t)VP_ * NG_ * 2;           // +4 MB
    size_t off_bv = off_W7 + (size_t)NIN_ * NG_ * 4;          // +56 KB
    size_t off_PQ = off_bv + (size_t)NG_ * 4;                 // +8 KB
    size_t need   = off_PQ + (size_t)B_ * 8 * 512 * 2 * sizeof(float);  // +2 MB
    if (ws_size < need) return;

    unsigned short* Aemb = (unsigned short*)((char*)d_ws + off_A);
    unsigned short* WT   = (unsigned short*)((char*)d_ws + off_WT);
    unsigned short* G    = (unsigned short*)((char*)d_ws + off_G);
    float*          W7   = (float*)((char*)d_ws + off_W7);
    float*          bvec = (float*)((char*)d_ws + off_bv);
    float*          PQ   = (float*)((char*)d_ws + off_PQ);

    prep<<<193, 256, 0, stream>>>(emb, Wn, bn, Wf, bfv, Wb, bb,
                                  Aemb, WT, W7, bvec);
    gemmG<<<128, 256, 0, stream>>>(Aemb, WT, bvec, G);
    scan<<<512, 512, 0, stream>>>(X, G, W7, PQ);
    final_out<<<64, 512, 0, stream>>>(X, G, W7, Wo, bo, PQ, out);
}